// Round 1
// baseline (30.414 us; speedup 1.0000x reference)
//
#include <hip/hip_runtime.h>
#include <math.h>

#define B_ 16
#define N_ 288
#define C_ 32
#define H_ 32
#define BN_ (B_ * N_)   // 4608
#define TI 8            // i-rows per block in pair kernel

// ---------------------------------------------------------------------------
// Kernel 1: GRU cell + sender/receiver projections. One wave (64 lanes) per
// node. Lanes 0..31 = "unit o" for 32-wide quantities; lane = unit for the
// 64-wide r_z output. fc2 bias is folded into the sender projection.
// ---------------------------------------------------------------------------
__global__ __launch_bounds__(256) void gru_proj_kernel(
    const float* __restrict__ inputs, const float* __restrict__ states,
    const float* __restrict__ rzW,    const float* __restrict__ rzb,
    const float* __restrict__ hcW,    const float* __restrict__ hcb,
    const float* __restrict__ c1W,    const float* __restrict__ c1b,
    const float* __restrict__ c2W,    const float* __restrict__ c2b,
    float* __restrict__ out_state,
    float* __restrict__ ps1, float* __restrict__ pr1,
    float* __restrict__ ps2, float* __restrict__ pr2)
{
    __shared__ float xsh[4][64];
    const int tid  = threadIdx.x;
    const int w    = tid >> 6;
    const int lane = tid & 63;
    const int o    = lane & 31;
    const int half = lane >> 5;
    const int node = blockIdx.x * 4 + w;   // BN_ % 4 == 0, always valid

    const float st = states[node * H_ + o];
    xsh[w][lane] = half ? st : inputs[node * C_ + o];
    __syncthreads();

    // r_z = sigmoid(x @ rzW + rzb) ; lane = output unit (64 units)
    float acc = rzb[lane];
    #pragma unroll
    for (int k = 0; k < 64; ++k)
        acc = fmaf(xsh[w][k], rzW[k * 64 + lane], acc);
    const float rz = 1.0f / (1.0f + __expf(-acc));

    const float r = __shfl(rz, o);        // r[o] (from lane o)
    const float z = __shfl(rz, o + 32);   // z[o] (from lane o+32)

    __syncthreads();                      // done reading x before overwrite
    if (half) xsh[w][lane] = r * st;      // x2 = concat(inputs, r*states)
    __syncthreads();

    // h_cand = tanh(x2 @ hcW + hcb): split-k across the two 32-lane halves
    float acc2 = 0.0f;
    const int kb = half * 32;
    #pragma unroll
    for (int k = 0; k < 32; ++k)
        acc2 = fmaf(xsh[w][kb + k], hcW[(kb + k) * 32 + o], acc2);
    acc2 += __shfl_xor(acc2, 32);
    const float hcand = tanhf(acc2 + hcb[o]);

    const float ns = z * st + (1.0f - z) * hcand;
    const float a  = fmaxf(ns, 0.0f);
    if (!half) out_state[node * H_ + o] = ns;

    __syncthreads();
    if (!half) xsh[w][o] = a;             // stage activation for projections
    __syncthreads();

    // Projections: half==0 -> sender rows [0,32) (+fc2 bias); half==1 ->
    // receiver rows [32,64). Both convs in one h-loop.
    float a1 = half ? 0.0f : c1b[o];
    float a2 = half ? 0.0f : c2b[o];
    const int rb = half * 32;
    #pragma unroll
    for (int h = 0; h < 32; ++h) {
        const float ah = xsh[w][h];
        a1 = fmaf(ah, c1W[(rb + h) * 32 + o], a1);
        a2 = fmaf(ah, c2W[(rb + h) * 32 + o], a2);
    }
    (half ? pr1 : ps1)[node * H_ + o] = a1;
    (half ? pr2 : ps2)[node * H_ + o] = a2;
}

// ---------------------------------------------------------------------------
// Kernel 2: pair conv. Block = (batch b, tile of TI sender rows i). Thread =
// receiver column j (0..287; 320 threads, last 32 idle). pr[j] and fc1
// weights live in VGPRs; ps rows are block-uniform -> scalar loads.
// ---------------------------------------------------------------------------
__global__ __launch_bounds__(320) void pair_kernel(
    const float* __restrict__ ps1, const float* __restrict__ pr1,
    const float* __restrict__ ps2, const float* __restrict__ pr2,
    const float* __restrict__ w1g, const float* __restrict__ b1g,
    const float* __restrict__ w2g, const float* __restrict__ b2g,
    float* __restrict__ out)
{
    const int j  = threadIdx.x;
    const int b  = blockIdx.x / (N_ / TI);
    const int i0 = (blockIdx.x % (N_ / TI)) * TI;
    if (j >= N_) return;

    const size_t rowbase = (size_t)(b * N_ + i0) * H_;
    float acc1[TI];
    float4 p[8];
    float  wv[32];

    // ---- conv1 (support) ----
    {
        const float4* prp = (const float4*)(pr1 + (size_t)(b * N_ + j) * H_);
        #pragma unroll
        for (int c = 0; c < 8; ++c) p[c] = prp[c];
        const float b1 = b1g[0];
        #pragma unroll
        for (int h = 0; h < 32; ++h) wv[h] = w1g[h];   // no 16B-align assumption
        #pragma unroll
        for (int ii = 0; ii < TI; ++ii) {
            const float4* sp = (const float4*)(ps1 + rowbase + (size_t)ii * H_);
            float a = b1;
            #pragma unroll
            for (int c = 0; c < 8; ++c) {
                const float4 sv = sp[c];   // uniform -> s_load
                a = fmaf(fmaxf(sv.x + p[c].x, 0.0f), wv[4 * c + 0], a);
                a = fmaf(fmaxf(sv.y + p[c].y, 0.0f), wv[4 * c + 1], a);
                a = fmaf(fmaxf(sv.z + p[c].z, 0.0f), wv[4 * c + 2], a);
                a = fmaf(fmaxf(sv.w + p[c].w, 0.0f), wv[4 * c + 3], a);
            }
            acc1[ii] = a;
        }
    }

    // ---- conv2 (mask) + epilogue ----
    {
        const float4* prp = (const float4*)(pr2 + (size_t)(b * N_ + j) * H_);
        #pragma unroll
        for (int c = 0; c < 8; ++c) p[c] = prp[c];
        const float b2 = b2g[0];
        #pragma unroll
        for (int h = 0; h < 32; ++h) wv[h] = w2g[h];
        float* orow = out + (size_t)(b * N_ + i0) * N_ + j;
        #pragma unroll
        for (int ii = 0; ii < TI; ++ii) {
            const float4* sp = (const float4*)(ps2 + rowbase + (size_t)ii * H_);
            float a = b2;
            #pragma unroll
            for (int c = 0; c < 8; ++c) {
                const float4 sv = sp[c];
                a = fmaf(fmaxf(sv.x + p[c].x, 0.0f), wv[4 * c + 0], a);
                a = fmaf(fmaxf(sv.y + p[c].y, 0.0f), wv[4 * c + 1], a);
                a = fmaf(fmaxf(sv.z + p[c].z, 0.0f), wv[4 * c + 2], a);
                a = fmaf(fmaxf(sv.w + p[c].w, 0.0f), wv[4 * c + 3], a);
            }
            const float sig = 1.0f / (1.0f + __expf(-a));
            orow[(size_t)ii * N_] = acc1[ii] * sig;
        }
    }
}

extern "C" void kernel_launch(void* const* d_in, const int* in_sizes, int n_in,
                              void* d_out, int out_size, void* d_ws, size_t ws_size,
                              hipStream_t stream) {
    const float* inputs = (const float*)d_in[0];
    const float* states = (const float*)d_in[1];
    const float* rzW    = (const float*)d_in[2];
    const float* rzb    = (const float*)d_in[3];
    const float* hcW    = (const float*)d_in[4];
    const float* hcb    = (const float*)d_in[5];
    const float* c1W    = (const float*)d_in[6];
    const float* c1b    = (const float*)d_in[7];
    const float* c1w1   = (const float*)d_in[8];
    const float* c1b1   = (const float*)d_in[9];
    const float* c2W    = (const float*)d_in[10];
    const float* c2b    = (const float*)d_in[11];
    const float* c2w1   = (const float*)d_in[12];
    const float* c2b1   = (const float*)d_in[13];

    float* out_support = (float*)d_out;
    float* out_state   = out_support + (size_t)BN_ * N_;

    float* ws  = (float*)d_ws;
    float* ps1 = ws;
    float* pr1 = ws + 1 * (size_t)BN_ * H_;
    float* ps2 = ws + 2 * (size_t)BN_ * H_;
    float* pr2 = ws + 3 * (size_t)BN_ * H_;

    gru_proj_kernel<<<BN_ / 4, 256, 0, stream>>>(
        inputs, states, rzW, rzb, hcW, hcb, c1W, c1b, c2W, c2b,
        out_state, ps1, pr1, ps2, pr2);

    pair_kernel<<<B_ * (N_ / TI), 320, 0, stream>>>(
        ps1, pr1, ps2, pr2, c1w1, c1b1, c2w1, c2b1, out_support);
}

// Round 2
// 25.687 us; speedup vs baseline: 1.1840x; 1.1840x over previous
//
#include <hip/hip_runtime.h>
#include <math.h>

#define B_ 16
#define N_ 288
#define C_ 32
#define H_ 32
#define BN_ (B_ * N_)     // 4608
#define NT 4              // nodes per wave in kernel 1
#define TI 6              // i-rows per block in kernel 2
#define NTILES (N_ / TI)  // 48

// ---------------------------------------------------------------------------
// Kernel 1: GRU cell + sender/receiver projections. One wave (64 lanes) per
// NT nodes. Nodes are block-uniform -> x rows are scalar (s_load) operands;
// each weight element is loaded ONCE per wave and reused across NT nodes
// (cuts weight L2 traffic 4x vs node-per-wave and gives 4 independent FMA
// chains for latency hiding). Lane = output unit (64 for rz; 32 duplicated
// across halves for hc; [sender|receiver] for projections).
// ---------------------------------------------------------------------------
__global__ __launch_bounds__(64) void gru_proj_kernel(
    const float* __restrict__ inputs, const float* __restrict__ states,
    const float* __restrict__ rzW,    const float* __restrict__ rzb,
    const float* __restrict__ hcW,    const float* __restrict__ hcb,
    const float* __restrict__ c1W,    const float* __restrict__ c1b,
    const float* __restrict__ c2W,    const float* __restrict__ c2b,
    float* __restrict__ out_state,
    float* __restrict__ ps1, float* __restrict__ pr1,
    float* __restrict__ ps2, float* __restrict__ pr2)
{
    const int lane  = threadIdx.x;     // 0..63
    const int o     = lane & 31;
    const int half  = lane >> 5;
    const int node0 = blockIdx.x * NT; // 1152 blocks cover 4608 nodes

    __shared__ float rs_sh[NT][32];    // r * state      (broadcast source)
    __shared__ float a_sh[NT][32];     // relu(new_state)

    // ---- r_z = sigmoid(x @ rzW + rzb); lane = out unit (64) ----
    float acc[NT];
    const float rzbias = rzb[lane];
    #pragma unroll
    for (int t = 0; t < NT; ++t) acc[t] = rzbias;

    #pragma unroll
    for (int k = 0; k < C_; ++k) {
        const float wk = rzW[k * 64 + lane];           // one 256B load / wave
        #pragma unroll
        for (int t = 0; t < NT; ++t)                   // scalar x operand
            acc[t] = fmaf(inputs[(node0 + t) * C_ + k], wk, acc[t]);
    }
    #pragma unroll
    for (int k = 0; k < H_; ++k) {
        const float wk = rzW[(C_ + k) * 64 + lane];
        #pragma unroll
        for (int t = 0; t < NT; ++t)
            acc[t] = fmaf(states[(node0 + t) * H_ + k], wk, acc[t]);
    }

    float z[NT], st[NT];
    #pragma unroll
    for (int t = 0; t < NT; ++t) {
        const float rzv = 1.0f / (1.0f + __expf(-acc[t]));
        const float r   = __shfl(rzv, o);        // r[o] to both halves
        z[t]  = __shfl(rzv, o + 32);             // z[o] to both halves
        st[t] = states[(node0 + t) * H_ + o];
        if (lane < 32) rs_sh[t][o] = r * st[t];
    }
    __syncthreads();

    // ---- h_cand = tanh(concat(x, r*state) @ hcW + hcb); halves duplicate ----
    float acc2[NT];
    #pragma unroll
    for (int t = 0; t < NT; ++t) acc2[t] = 0.0f;

    #pragma unroll
    for (int k = 0; k < C_; ++k) {
        const float wk = hcW[k * H_ + o];
        #pragma unroll
        for (int t = 0; t < NT; ++t)
            acc2[t] = fmaf(inputs[(node0 + t) * C_ + k], wk, acc2[t]);
    }
    #pragma unroll
    for (int q = 0; q < 8; ++q) {                 // k = 32..63 via LDS quads
        float4 rq[NT];
        #pragma unroll
        for (int t = 0; t < NT; ++t)
            rq[t] = *(const float4*)&rs_sh[t][q * 4];   // broadcast b128
        #pragma unroll
        for (int k4 = 0; k4 < 4; ++k4) {
            const float wk = hcW[(C_ + q * 4 + k4) * H_ + o];
            #pragma unroll
            for (int t = 0; t < NT; ++t)
                acc2[t] = fmaf(((const float*)&rq[t])[k4], wk, acc2[t]);
        }
    }

    const float hcbias = hcb[o];
    #pragma unroll
    for (int t = 0; t < NT; ++t) {
        // tanh(x) = 1 - 2/(exp(2x)+1)  (fast, ~1e-6 abs err, saturates right)
        const float e  = __expf(2.0f * (acc2[t] + hcbias));
        const float hc = 1.0f - 2.0f / (e + 1.0f);
        const float ns = z[t] * st[t] + (1.0f - z[t]) * hc;
        if (lane < 32) out_state[(node0 + t) * H_ + o] = ns;
        const float av = fmaxf(ns, 0.0f);
        if (lane < 32) a_sh[t][o] = av;
    }
    __syncthreads();

    // ---- projections: lane = [sender unit o | receiver unit o] ----
    const int rb = half * 32;                     // weight row block
    float p1[NT], p2[NT];
    const float b1v = c1b[o], b2v = c2b[o];
    #pragma unroll
    for (int t = 0; t < NT; ++t) {
        p1[t] = half ? 0.0f : b1v;                // fc2 bias folded into sender
        p2[t] = half ? 0.0f : b2v;
    }
    #pragma unroll
    for (int q = 0; q < 8; ++q) {
        float4 aq[NT];
        #pragma unroll
        for (int t = 0; t < NT; ++t)
            aq[t] = *(const float4*)&a_sh[t][q * 4];    // broadcast b128
        #pragma unroll
        for (int k4 = 0; k4 < 4; ++k4) {
            const int h    = q * 4 + k4;
            const float w1 = c1W[(rb + h) * H_ + o];
            const float w2 = c2W[(rb + h) * H_ + o];
            #pragma unroll
            for (int t = 0; t < NT; ++t) {
                const float av = ((const float*)&aq[t])[k4];
                p1[t] = fmaf(av, w1, p1[t]);
                p2[t] = fmaf(av, w2, p2[t]);
            }
        }
    }
    float* d1 = half ? pr1 : ps1;
    float* d2 = half ? pr2 : ps2;
    #pragma unroll
    for (int t = 0; t < NT; ++t) {
        d1[(node0 + t) * H_ + o] = p1[t];
        d2[(node0 + t) * H_ + o] = p2[t];
    }
}

// ---------------------------------------------------------------------------
// Kernel 2: pair conv. Block = (batch b, tile of TI sender rows). Thread =
// receiver column j. pr[j] in VGPRs; ps rows + fc1 weights are uniform ->
// scalar loads. Two accumulator chains (even/odd h) per row for ILP/packing.
// ---------------------------------------------------------------------------
__global__ __launch_bounds__(320) void pair_kernel(
    const float* __restrict__ ps1, const float* __restrict__ pr1,
    const float* __restrict__ ps2, const float* __restrict__ pr2,
    const float* __restrict__ w1g, const float* __restrict__ b1g,
    const float* __restrict__ w2g, const float* __restrict__ b2g,
    float* __restrict__ out)
{
    const int j  = threadIdx.x;
    const int b  = blockIdx.x / NTILES;
    const int i0 = (blockIdx.x % NTILES) * TI;
    if (j >= N_) return;

    const size_t rowbase = (size_t)(b * N_ + i0) * H_;
    float acc1[TI];
    float4 p[8];
    float  wv[32];

    // ---- conv1 (support) ----
    {
        const float4* prp = (const float4*)(pr1 + (size_t)(b * N_ + j) * H_);
        #pragma unroll
        for (int c = 0; c < 8; ++c) p[c] = prp[c];
        #pragma unroll
        for (int h = 0; h < 32; ++h) wv[h] = w1g[h];   // uniform -> SGPR
        const float b1 = b1g[0];
        #pragma unroll
        for (int ii = 0; ii < TI; ++ii) {
            const float4* sp = (const float4*)(ps1 + rowbase + (size_t)ii * H_);
            float aA = b1, aB = 0.0f;
            #pragma unroll
            for (int c = 0; c < 8; ++c) {
                const float4 sv = sp[c];               // uniform -> s_load
                const float t0 = fmaxf(sv.x + p[c].x, 0.0f);
                const float t1 = fmaxf(sv.y + p[c].y, 0.0f);
                const float t2 = fmaxf(sv.z + p[c].z, 0.0f);
                const float t3 = fmaxf(sv.w + p[c].w, 0.0f);
                aA = fmaf(t0, wv[4 * c + 0], aA);
                aB = fmaf(t1, wv[4 * c + 1], aB);
                aA = fmaf(t2, wv[4 * c + 2], aA);
                aB = fmaf(t3, wv[4 * c + 3], aB);
            }
            acc1[ii] = aA + aB;
        }
    }

    // ---- conv2 (mask) + epilogue ----
    {
        const float4* prp = (const float4*)(pr2 + (size_t)(b * N_ + j) * H_);
        #pragma unroll
        for (int c = 0; c < 8; ++c) p[c] = prp[c];
        #pragma unroll
        for (int h = 0; h < 32; ++h) wv[h] = w2g[h];
        const float b2 = b2g[0];
        float* orow = out + (size_t)(b * N_ + i0) * N_ + j;
        #pragma unroll
        for (int ii = 0; ii < TI; ++ii) {
            const float4* sp = (const float4*)(ps2 + rowbase + (size_t)ii * H_);
            float aA = b2, aB = 0.0f;
            #pragma unroll
            for (int c = 0; c < 8; ++c) {
                const float4 sv = sp[c];
                const float t0 = fmaxf(sv.x + p[c].x, 0.0f);
                const float t1 = fmaxf(sv.y + p[c].y, 0.0f);
                const float t2 = fmaxf(sv.z + p[c].z, 0.0f);
                const float t3 = fmaxf(sv.w + p[c].w, 0.0f);
                aA = fmaf(t0, wv[4 * c + 0], aA);
                aB = fmaf(t1, wv[4 * c + 1], aB);
                aA = fmaf(t2, wv[4 * c + 2], aA);
                aB = fmaf(t3, wv[4 * c + 3], aB);
            }
            const float m   = aA + aB;
            const float sig = 1.0f / (1.0f + __expf(-m));
            orow[(size_t)ii * N_] = acc1[ii] * sig;
        }
    }
}

extern "C" void kernel_launch(void* const* d_in, const int* in_sizes, int n_in,
                              void* d_out, int out_size, void* d_ws, size_t ws_size,
                              hipStream_t stream) {
    const float* inputs = (const float*)d_in[0];
    const float* states = (const float*)d_in[1];
    const float* rzW    = (const float*)d_in[2];
    const float* rzb    = (const float*)d_in[3];
    const float* hcW    = (const float*)d_in[4];
    const float* hcb    = (const float*)d_in[5];
    const float* c1W    = (const float*)d_in[6];
    const float* c1b    = (const float*)d_in[7];
    const float* c1w1   = (const float*)d_in[8];
    const float* c1b1   = (const float*)d_in[9];
    const float* c2W    = (const float*)d_in[10];
    const float* c2b    = (const float*)d_in[11];
    const float* c2w1   = (const float*)d_in[12];
    const float* c2b1   = (const float*)d_in[13];

    float* out_support = (float*)d_out;
    float* out_state   = out_support + (size_t)BN_ * N_;

    float* ws  = (float*)d_ws;
    float* ps1 = ws;
    float* pr1 = ws + 1 * (size_t)BN_ * H_;
    float* ps2 = ws + 2 * (size_t)BN_ * H_;
    float* pr2 = ws + 3 * (size_t)BN_ * H_;

    gru_proj_kernel<<<BN_ / NT, 64, 0, stream>>>(
        inputs, states, rzW, rzb, hcW, hcb, c1W, c1b, c2W, c2b,
        out_state, ps1, pr1, ps2, pr2);

    pair_kernel<<<B_ * NTILES, 320, 0, stream>>>(
        ps1, pr1, ps2, pr2, c1w1, c1b1, c2w1, c2b1, out_support);
}